// Round 1
// baseline (403.354 us; speedup 1.0000x reference)
//
#include <hip/hip_runtime.h>
#include <math.h>

#define T_LEN 512
#define B_N   1024
#define K_N   48
#define START_TAG (K_N - 2)
#define STOP_TAG  (K_N - 1)
#define NEG   -10000.0f

// One wave (64 threads) per batch. Lane j owns alpha[j] and row j of
// E = exp(transitions) in 48 VGPRs. Forward recursion:
//   new_alpha[j] = feat[t,b,j] + m + log( sum_k E[j,k] * exp(alpha[k]-m) )
// which is exactly logsumexp_k(alpha[k] + trans[j,k]) + feat, but with
// K exps per step instead of K^2 (E precomputed once).
__global__ __launch_bounds__(64) void crf_fused_kernel(
    const float* __restrict__ feats,    // (T, B, K)
    const float* __restrict__ trans,    // (K, K)
    const int*   __restrict__ tags,     // (B, T)
    const int*   __restrict__ lengths,  // (B,)
    float* __restrict__ out)            // scalar accumulator
{
    const int b    = blockIdx.x;
    const int lane = threadIdx.x;
    const int len  = lengths[b];

    __shared__ __align__(16) float p_lds[64];

    // Preload E row for this lane (j = lane). Lanes >= K get zeros.
    float Erow[K_N];
    if (lane < K_N) {
        #pragma unroll
        for (int k = 0; k < K_N; ++k)
            Erow[k] = __expf(trans[lane * K_N + k]);
    } else {
        #pragma unroll
        for (int k = 0; k < K_N; ++k) Erow[k] = 0.0f;
    }

    float alpha = (lane == START_TAG) ? 0.0f
                : ((lane < K_N) ? NEG : -INFINITY);

    const float* fb = feats + (size_t)b * K_N;  // feats[t*B*K + b*K + j]
    float feat = (lane < K_N) ? fb[lane] : 0.0f;

    for (int t = 0; t < len; ++t) {
        // Software-prefetch next timestep's emission.
        float feat_next = 0.0f;
        if (t + 1 < len && lane < K_N)
            feat_next = fb[(size_t)(t + 1) * (B_N * K_N) + lane];

        // m = max over lanes of alpha (lanes >= K hold -inf)
        float m = alpha;
        #pragma unroll
        for (int off = 32; off >= 1; off >>= 1)
            m = fmaxf(m, __shfl_xor(m, off));

        // p[lane] = exp(alpha - m), shared via LDS broadcast
        p_lds[lane] = __expf(alpha - m);
        __syncthreads();

        // dot(Erow, p) with 4 accumulators for ILP
        const float4* p4 = (const float4*)p_lds;
        float a0 = 0.f, a1 = 0.f, a2 = 0.f, a3 = 0.f;
        #pragma unroll
        for (int q = 0; q < K_N / 4; ++q) {
            float4 v = p4[q];
            a0 = fmaf(Erow[4 * q + 0], v.x, a0);
            a1 = fmaf(Erow[4 * q + 1], v.y, a1);
            a2 = fmaf(Erow[4 * q + 2], v.z, a2);
            a3 = fmaf(Erow[4 * q + 3], v.w, a3);
        }
        float sum = (a0 + a1) + (a2 + a3);
        __syncthreads();  // protect p_lds before next iteration's write

        float na = m + __logf(sum) + feat;   // log(0) = -inf is correct here
        alpha = (lane < K_N) ? na : -INFINITY;
        feat = feat_next;
    }

    // log_z = logsumexp_j(alpha[j] + trans[STOP, j])
    float v = (lane < K_N) ? alpha + trans[STOP_TAG * K_N + lane] : -INFINITY;
    float mz = v;
    #pragma unroll
    for (int off = 32; off >= 1; off >>= 1)
        mz = fmaxf(mz, __shfl_xor(mz, off));
    float e = __expf(v - mz);
    float se = e;
    #pragma unroll
    for (int off = 32; off >= 1; off >>= 1)
        se += __shfl_xor(se, off);
    float log_z = mz + __logf(se);

    // Gold path score: lanes stripe over t.
    float gsum = 0.0f;
    for (int t = lane; t < len; t += 64) {
        int next = tags[(size_t)b * T_LEN + t];
        int prev = (t == 0) ? START_TAG : tags[(size_t)b * T_LEN + t - 1];
        gsum += trans[next * K_N + prev]
              + fb[(size_t)t * (B_N * K_N) + next];
    }
    #pragma unroll
    for (int off = 32; off >= 1; off >>= 1)
        gsum += __shfl_xor(gsum, off);

    if (lane == 0) {
        int last = tags[(size_t)b * T_LEN + len - 1];
        float gold = gsum + trans[STOP_TAG * K_N + last];
        atomicAdd(out, log_z - gold);
    }
}

extern "C" void kernel_launch(void* const* d_in, const int* in_sizes, int n_in,
                              void* d_out, int out_size, void* d_ws, size_t ws_size,
                              hipStream_t stream) {
    const float* feats   = (const float*)d_in[0];
    const float* trans   = (const float*)d_in[1];
    const int*   tags    = (const int*)d_in[2];
    const int*   lengths = (const int*)d_in[3];
    float* out = (float*)d_out;

    hipMemsetAsync(out, 0, sizeof(float) * out_size, stream);
    crf_fused_kernel<<<B_N, 64, 0, stream>>>(feats, trans, tags, lengths, out);
}

// Round 2
// 396.608 us; speedup vs baseline: 1.0170x; 1.0170x over previous
//
#include <hip/hip_runtime.h>
#include <math.h>

#define T_LEN 512
#define B_N   1024
#define K_N   48
#define START_TAG (K_N - 2)
#define STOP_TAG  (K_N - 1)
#define NEG   -10000.0f

// One wave (64 threads) per batch, lane j owns state j.
// Scaled-exponential domain: q_j = exp(alpha_j - C), C a per-batch scalar.
// Step:  s_j = sum_k E[j,k] * q_k      (E = exp(trans), in VGPRs)
//        q_j' = F_j * s_j * inv,  F_j = exp(feat[t,b,j]), inv = 1/q_0
//        C   += log(q_0)
// exp(feat), rcp, log, readlane are all OFF the critical chain (computed
// during the LDS roundtrip of the dot's broadcast). No shfl butterfly.
__global__ __launch_bounds__(64) void crf_fused_kernel(
    const float* __restrict__ feats,    // (T, B, K)
    const float* __restrict__ trans,    // (K, K)
    const int*   __restrict__ tags,     // (B, T)
    const int*   __restrict__ lengths,  // (B,)
    float* __restrict__ out)
{
    const int b    = blockIdx.x;
    const int lane = threadIdx.x;
    const int len  = lengths[b];

    __shared__ __align__(16) float q_lds[2][64];

    // E row for this lane. exp(-10000) == 0 exactly in fp32, which
    // reproduces the NEG masking (row START dies, column STOP blocked).
    float Erow[K_N];
    if (lane < K_N) {
        #pragma unroll
        for (int k = 0; k < K_N; ++k)
            Erow[k] = __expf(trans[lane * K_N + k]);
    } else {
        #pragma unroll
        for (int k = 0; k < K_N; ++k) Erow[k] = 0.0f;
    }

    const float*  fb      = feats + (size_t)b * K_N;
    const size_t  strideT = (size_t)B_N * K_N;

    // q(0) = exp(alpha0): 1 at START, 0 elsewhere (exp(NEG) underflows to 0,
    // matching the reference's fp32 arithmetic). Lanes >= K: Erow=0 -> q stays 0.
    float q = (lane == START_TAG) ? 1.0f : 0.0f;
    float C = 0.0f;

    // Distance-2 feat prefetch pipeline (raw values r1=feat[t+1], r2=feat[t+2]).
    float f0 = (lane < K_N) ? fb[lane] : 0.0f;
    float r1 = (1 < len && lane < K_N) ? fb[strideT + lane] : 0.0f;
    float r2 = (2 < len && lane < K_N) ? fb[2 * strideT + lane] : 0.0f;
    float F_cur = __expf(f0);

    for (int t = 0; t < len; ++t) {
        const int bi = t & 1;
        q_lds[bi][lane] = q;

        // ---- off-critical-path work (overlaps LDS write/read latency) ----
        float q0 = __uint_as_float(__builtin_amdgcn_readlane(__float_as_uint(q), 0));
        float inv;
        if (q0 > 0.0f) {            // false only at t==0 (uniform branch)
            inv = 1.0f / q0;
            C  += __logf(q0);
        } else {
            inv = 1.0f;
        }
        float scale  = F_cur * inv;
        float F_next = __expf(r1);            // exp(feat[t+1])
        float rload  = 0.0f;
        if (t + 3 < len && lane < K_N)
            rload = fb[(size_t)(t + 3) * strideT + lane];

        __syncthreads();   // write of q(t) visible; also fences buffer reuse

        // ---- critical path: broadcast dot, 8 accumulators (6-deep chains) ----
        const float4* q4 = (const float4*)q_lds[bi];
        float acc[8] = {0.f, 0.f, 0.f, 0.f, 0.f, 0.f, 0.f, 0.f};
        #pragma unroll
        for (int m = 0; m < K_N / 4; ++m) {
            float4 v = q4[m];
            acc[(4 * m + 0) & 7] = fmaf(Erow[4 * m + 0], v.x, acc[(4 * m + 0) & 7]);
            acc[(4 * m + 1) & 7] = fmaf(Erow[4 * m + 1], v.y, acc[(4 * m + 1) & 7]);
            acc[(4 * m + 2) & 7] = fmaf(Erow[4 * m + 2], v.z, acc[(4 * m + 2) & 7]);
            acc[(4 * m + 3) & 7] = fmaf(Erow[4 * m + 3], v.w, acc[(4 * m + 3) & 7]);
        }
        float s = ((acc[0] + acc[1]) + (acc[2] + acc[3]))
                + ((acc[4] + acc[5]) + (acc[6] + acc[7]));

        q = s * scale;          // lanes >= K: s==0 -> q==0
        F_cur = F_next; r1 = r2; r2 = rload;
    }

    // log_z = C + log( sum_j q_j * exp(trans[STOP,j]) ), via lse for safety.
    float v = (lane < K_N && q > 0.0f)
            ? C + __logf(q) + trans[STOP_TAG * K_N + lane] : -INFINITY;
    float mz = v;
    #pragma unroll
    for (int off = 32; off >= 1; off >>= 1)
        mz = fmaxf(mz, __shfl_xor(mz, off));
    float e = __expf(v - mz);
    float se = e;
    #pragma unroll
    for (int off = 32; off >= 1; off >>= 1)
        se += __shfl_xor(se, off);
    float log_z = mz + __logf(se);

    // Gold path score: lanes stripe over t.
    float gsum = 0.0f;
    for (int t = lane; t < len; t += 64) {
        int next = tags[(size_t)b * T_LEN + t];
        int prev = (t == 0) ? START_TAG : tags[(size_t)b * T_LEN + t - 1];
        gsum += trans[next * K_N + prev]
              + fb[(size_t)t * strideT + next];
    }
    #pragma unroll
    for (int off = 32; off >= 1; off >>= 1)
        gsum += __shfl_xor(gsum, off);

    if (lane == 0) {
        int last = tags[(size_t)b * T_LEN + len - 1];
        float gold = gsum + trans[STOP_TAG * K_N + last];
        atomicAdd(out, log_z - gold);
    }
}

extern "C" void kernel_launch(void* const* d_in, const int* in_sizes, int n_in,
                              void* d_out, int out_size, void* d_ws, size_t ws_size,
                              hipStream_t stream) {
    const float* feats   = (const float*)d_in[0];
    const float* trans   = (const float*)d_in[1];
    const int*   tags    = (const int*)d_in[2];
    const int*   lengths = (const int*)d_in[3];
    float* out = (float*)d_out;

    hipMemsetAsync(out, 0, sizeof(float) * out_size, stream);
    crf_fused_kernel<<<B_N, 64, 0, stream>>>(feats, trans, tags, lengths, out);
}